// Round 15
// baseline (145.826 us; speedup 1.0000x reference)
//
#include <hip/hip_runtime.h>
#include <hip/hip_bf16.h>

typedef unsigned short ushort_t;
typedef __attribute__((ext_vector_type(8))) __bf16 bf16x8;
typedef __attribute__((ext_vector_type(4))) float f32x4;
typedef __attribute__((ext_vector_type(4))) unsigned short us4;

#define S0 2048
#define DM 768
#define NH 12
#define DH 64
#define KS 2368   // allocated key rows per batch (2048 real + bias pad, global key at 2304)
#define GK 2304   // global-key row index

__device__ __forceinline__ float bf2f(ushort_t h){
  union{unsigned u; float f;} x; x.u = ((unsigned)h)<<16; return x.f;
}
__device__ __forceinline__ ushort_t f2bf(float f){
  union{float f; unsigned u;} x; x.f = f;
  unsigned r = (x.u + 0x7FFFu + ((x.u>>16)&1u))>>16;
  return (ushort_t)r;
}

// fast GELU (sigmoid form of the tanh approximation; ~8 VALU vs ~35 for erff;
// saturates correctly at both ends). |err| vs exact < 5e-4.
__device__ __forceinline__ float gelu_fast(float u){
  const float t = u*u;
  const float arg = u*(-1.5957691216f - 0.0713548163f*t);
  return u / (1.f + __expf(arg));
}

typedef void as1_void __attribute__((address_space(1)));
typedef void as3_void __attribute__((address_space(3)));
__device__ __forceinline__ void lds_cp16(const void* g, void* s){
  __builtin_amdgcn_global_load_lds((as1_void*)g, (as3_void*)s, 16, 0, 0);
}

// bijective XCD-chunk swizzle (m204)
__device__ __forceinline__ int xcd_swizzle(int bid, int nwg){
  const int q8 = nwg>>3, r8 = nwg&7;
  const int xcd = bid & 7, sub = bid >> 3;
  return (xcd < r8 ? xcd*(q8+1) : r8*(q8+1) + (xcd-r8)*q8) + sub;
}

// ---------------------------------------------------------------------------
// Batched prep: weight transposes + x cvt + bias concat + K/Vt bias fills
// ---------------------------------------------------------------------------
__global__ __launch_bounds__(256)
void prep_kernel(const float* __restrict__ Wq, const float* __restrict__ Wk,
                 const float* __restrict__ Wv, const float* __restrict__ W1,
                 const float* __restrict__ W2, const float* __restrict__ x,
                 const float* __restrict__ bq, const float* __restrict__ bk,
                 const float* __restrict__ bv,
                 ushort_t* __restrict__ WtQ, ushort_t* __restrict__ WtK,
                 ushort_t* __restrict__ WtV, ushort_t* __restrict__ Wt1,
                 ushort_t* __restrict__ Wt2, ushort_t* __restrict__ xb,
                 float* __restrict__ bqkv, ushort_t* __restrict__ Kb,
                 ushort_t* __restrict__ Vtb)
{
  __shared__ ushort_t tile[64][72];
  const int id = blockIdx.x, t = threadIdx.x;
  if (id < 1584){
    const float* src; ushort_t* dst; int K, N, bx, by;
    if (id < 432){
      const int m = id/144, r = id%144;
      src = (m==0)?Wq:((m==1)?Wk:Wv);
      dst = (m==0)?WtQ:((m==1)?WtK:WtV);
      K=768; N=768; bx=r%12; by=r/12;
    } else if (id < 1008){
      const int r = id-432; src=W1; dst=Wt1; K=768; N=3072; bx=r%48; by=r/48;
    } else {
      const int r = id-1008; src=W2; dst=Wt2; K=3072; N=768; bx=r%12; by=r/12;
    }
    const int n0 = bx*64, k0 = by*64;
    #pragma unroll
    for (int p=0; p<2; p++){
      int r = (t>>3) + p*32, c = (t&7)*8;
      const float* sp = src + (size_t)(k0+r)*N + n0 + c;
      const float4 a = *(const float4*)sp;
      const float4 b = *(const float4*)(sp+4);
      ushort_t v[8] = { f2bf(a.x), f2bf(a.y), f2bf(a.z), f2bf(a.w),
                        f2bf(b.x), f2bf(b.y), f2bf(b.z), f2bf(b.w) };
      *(int4*)&tile[r][c] = *(int4*)v;
    }
    __syncthreads();
    #pragma unroll
    for (int p=0; p<2; p++){
      int n = t&63, kc = (t>>6)*8 + p*32;
      ushort_t v[8];
      #pragma unroll
      for (int e=0; e<8; e++) v[e] = tile[kc+e][n];
      *(int4*)(dst + (size_t)(n0+n)*K + k0 + kc) = *(int4*)v;
    }
  } else if (id < 3120){
    const int i = (id-1584)*2048 + t*8;
    const float4 a = *(const float4*)(x+i);
    const float4 b = *(const float4*)(x+i+4);
    ushort_t v[8] = { f2bf(a.x), f2bf(a.y), f2bf(a.z), f2bf(a.w),
                      f2bf(b.x), f2bf(b.y), f2bf(b.z), f2bf(b.w) };
    *(int4*)(xb+i) = *(int4*)v;
  } else if (id < 3129){
    const int i = (id-3120)*256 + t;
    if (i < 2304)
      bqkv[i] = (i < 768) ? bq[i] : (i < 1536) ? bk[i-768] : bv[i-1536];
  } else if (id < 3369){
    const int i = (id-3129)*2048 + t*8;
    const int col = i % DM;
    const int rr  = i / DM;
    const int row = S0 + rr % (KS-S0);
    const int bb  = rr / (KS-S0);
    const float4 a = *(const float4*)(bk+col);
    const float4 b4 = *(const float4*)(bk+col+4);
    ushort_t v[8] = { f2bf(a.x), f2bf(a.y), f2bf(a.z), f2bf(a.w),
                      f2bf(b4.x), f2bf(b4.y), f2bf(b4.z), f2bf(b4.w) };
    *(int4*)&Kb[(size_t)bb*KS*DM + (size_t)row*DM + col] = *(int4*)v;
  } else {
    const int rid = id - 3369;
    const int h = (rid>>6) % NH;
    const int dd = rid & 63;
    const ushort_t val = f2bf(bv[h*64+dd]);
    if (t < 80){
      us4 pk = {val, val, val, val};
      *(us4*)&Vtb[(size_t)rid*KS + S0 + t*4] = pk;
    }
  }
}

// ---------------------------------------------------------------------------
// GEMM 128 x (32*NF), BK=64, 4 waves (2x2). m97 single-buffer structure,
// both-sides XOR swizzle (T2), XCD block swizzle (T1).
// EPI: 2 fast GELU, 4 fused-QKV routing (Q scaled / K batched / Vt direct).
// ---------------------------------------------------------------------------
template<int EPI, int NF, typename OT>
__global__ __launch_bounds__(256)
void gemm_bt(const ushort_t* __restrict__ A, const ushort_t* __restrict__ Bt,
             const float* __restrict__ bias, OT* __restrict__ C,
             ushort_t* __restrict__ C2, ushort_t* __restrict__ C3,
             int K, int ldc, long long ldcb, int nbx)
{
  __shared__ ushort_t As[128*64];
  __shared__ ushort_t Bs[NF*32*64];
  const int tid = threadIdx.x, wid = tid>>6, l = tid&63;

  const int wg = xcd_swizzle(blockIdx.x, gridDim.x);
  const int bx = wg % nbx, by = wg / nbx;
  const int m0 = by*128, n0 = bx*(NF*32);

  const int wm = wid>>1, wn = wid&1;
  const int lq = l&15, lg = l>>4;
  const int xa = lq&7;

  f32x4 acc[4][NF];
  const f32x4 zero = {0.f,0.f,0.f,0.f};
  #pragma unroll
  for (int i=0;i<4;i++)
    #pragma unroll
    for (int j=0;j<NF;j++) acc[i][j] = zero;

  const int swzc = ((l&7) ^ ((l>>3)&7)) * 8;
  const ushort_t* Ag = A  + (size_t)(m0 + wid*32 + (l>>3))*K + swzc;
  const ushort_t* Bg = Bt + (size_t)(n0 + wid*(NF*8) + (l>>3))*K + swzc;

  for (int k0=0; k0<K; k0+=64){
    #pragma unroll
    for (int i=0;i<4;i++)
      lds_cp16(Ag + (size_t)i*8*K + k0, As + wid*2048 + i*512);
    #pragma unroll
    for (int i=0;i<NF;i++)
      lds_cp16(Bg + (size_t)i*8*K + k0, Bs + wid*(NF*512) + i*512);
    __syncthreads();
    #pragma unroll
    for (int kk=0; kk<64; kk+=32){
      bf16x8 af[4], bfr[NF];
      #pragma unroll
      for (int mi=0;mi<4;mi++)
        af[mi] = *(const bf16x8*)&As[(wm*64+mi*16+lq)*64 + ((((kk>>3)+lg)^xa)<<3)];
      #pragma unroll
      for (int ni=0;ni<NF;ni++)
        bfr[ni] = *(const bf16x8*)&Bs[(wn*(NF*16)+ni*16+lq)*64 + ((((kk>>3)+lg)^xa)<<3)];
      #pragma unroll
      for (int mi=0;mi<4;mi++)
        #pragma unroll
        for (int ni=0;ni<NF;ni++)
          acc[mi][ni] = __builtin_amdgcn_mfma_f32_16x16x32_bf16(af[mi], bfr[ni], acc[mi][ni], 0,0,0);
    }
    __syncthreads();
  }

  if (EPI==4){
    const int seg = n0 / 768;                 // 0:Q 1:K 2:Vt (64-wide tiles never straddle)
    if (seg == 2){
      #pragma unroll
      for (int mi=0;mi<4;mi++){
        const int mrow = m0 + wm*64 + mi*16 + lg*4;
        const int bb = mrow>>11, key = mrow&2047;
        #pragma unroll
        for (int ni=0;ni<NF;ni++){
          const int ncol = n0 + wn*(NF*16) + ni*16 + lq;
          const int col = ncol - 1536;
          const float bvv = bias[ncol];
          us4 pk;
          #pragma unroll
          for (int r=0;r<4;r++) pk[r] = f2bf(acc[mi][ni][r] + bvv);
          *(us4*)&C3[((size_t)(bb*NH + (col>>6))*64 + (col&63))*KS + key] = pk;
        }
      }
      return;
    }
    ushort_t* dst = (seg==0) ? (ushort_t*)C : C2;
    const long long bstride = (seg==1) ? (long long)KS*DM : 2048LL*DM;
    const float sc = (seg==0) ? 0.125f : 1.f;
    #pragma unroll
    for (int mi=0;mi<4;mi++){
      const int mrow = m0 + wm*64 + mi*16 + lg*4;
      #pragma unroll
      for (int ni=0;ni<NF;ni++){
        const int ncol = n0 + wn*(NF*16) + ni*16 + lq;
        const float bv = bias[ncol];
        const int col = ncol - seg*768;
        #pragma unroll
        for (int r=0;r<4;r++){
          const int m = mrow + r;
          const float v = (acc[mi][ni][r] + bv)*sc;
          dst[(size_t)((long long)(m>>11)*bstride) + (size_t)(m&2047)*DM + col] = f2bf(v);
        }
      }
    }
    return;
  }

  #pragma unroll
  for (int mi=0;mi<4;mi++){
    const int mrow = m0 + wm*64 + mi*16 + lg*4;
    #pragma unroll
    for (int ni=0;ni<NF;ni++){
      const int ncol = n0 + wn*(NF*16) + ni*16 + lq;
      const float bv = bias[ncol];
      #pragma unroll
      for (int r=0;r<4;r++){
        const int m = mrow + r;
        float v = acc[mi][ni][r] + bv;
        if (EPI==2) v = gelu_fast(v);
        const size_t caddr = (size_t)((long long)(m>>11)*ldcb) + (size_t)(m&2047)*ldc + ncol;
        C[caddr] = f2bf(v);
      }
    }
  }
}

// ---------------------------------------------------------------------------
// FFN2 split-K=2, 128x64 tiles, m97 single-buffer loop. grid = 768 WGs.
// Partials fp32, reduced by ffn2_reduce (no atomics).
// ---------------------------------------------------------------------------
__global__ __launch_bounds__(256)
void gemm_sk(const ushort_t* __restrict__ A, const ushort_t* __restrict__ Bt,
             float* __restrict__ part)
{
  __shared__ ushort_t As[128*64];
  __shared__ ushort_t Bs[64*64];
  const int tid = threadIdx.x, wid = tid>>6, l = tid&63;

  const int wg = xcd_swizzle(blockIdx.x, gridDim.x);
  const int p = wg / 384, rem = wg % 384;      // p: K-half
  const int bx = rem % 12, by = rem / 12;
  const int m0 = by*128, n0 = bx*64;
  const int kbeg = p*1536;

  const int wm = wid>>1, wn = wid&1;
  const int lq = l&15, lg = l>>4;
  const int xa = lq&7;

  f32x4 acc[4][2];
  const f32x4 zero = {0.f,0.f,0.f,0.f};
  #pragma unroll
  for (int i=0;i<4;i++){ acc[i][0]=zero; acc[i][1]=zero; }

  const int swzc = ((l&7) ^ ((l>>3)&7)) * 8;
  const ushort_t* Ag = A  + (size_t)(m0 + wid*32 + (l>>3))*3072 + kbeg + swzc;
  const ushort_t* Bg = Bt + (size_t)(n0 + wid*16 + (l>>3))*3072 + kbeg + swzc;

  for (int k0=0; k0<1536; k0+=64){
    #pragma unroll
    for (int i=0;i<4;i++)
      lds_cp16(Ag + (size_t)i*8*3072 + k0, As + wid*2048 + i*512);
    #pragma unroll
    for (int i=0;i<2;i++)
      lds_cp16(Bg + (size_t)i*8*3072 + k0, Bs + wid*1024 + i*512);
    __syncthreads();
    #pragma unroll
    for (int kk=0; kk<64; kk+=32){
      bf16x8 af[4], bfr[2];
      #pragma unroll
      for (int mi=0;mi<4;mi++)
        af[mi] = *(const bf16x8*)&As[(wm*64+mi*16+lq)*64 + ((((kk>>3)+lg)^xa)<<3)];
      #pragma unroll
      for (int ni=0;ni<2;ni++)
        bfr[ni] = *(const bf16x8*)&Bs[(wn*32+ni*16+lq)*64 + ((((kk>>3)+lg)^xa)<<3)];
      #pragma unroll
      for (int mi=0;mi<4;mi++)
        #pragma unroll
        for (int ni=0;ni<2;ni++)
          acc[mi][ni] = __builtin_amdgcn_mfma_f32_16x16x32_bf16(af[mi], bfr[ni], acc[mi][ni], 0,0,0);
    }
    __syncthreads();
  }

  float* dst = part + (size_t)p*4096*DM;
  #pragma unroll
  for (int mi=0;mi<4;mi++){
    const int mrow = m0 + wm*64 + mi*16 + lg*4;
    #pragma unroll
    for (int ni=0;ni<2;ni++){
      const int ncol = n0 + wn*32 + ni*16 + lq;
      #pragma unroll
      for (int r=0;r<4;r++)
        dst[(size_t)(mrow+r)*DM + ncol] = acc[mi][ni][r];
    }
  }
}

// ---------------------------------------------------------------------------
// FFN2 reduce: out = part0 + part1 + xn + b2. 8 elems/thread, 1536 WGs.
// ---------------------------------------------------------------------------
__global__ __launch_bounds__(256)
void ffn2_reduce(const float* __restrict__ part, const ushort_t* __restrict__ xn,
                 const float* __restrict__ b2, float* __restrict__ out)
{
  const int i = (blockIdx.x*256 + threadIdx.x)*8;
  const int col = i % DM;                          // 8-aligned, never wraps
  const float* p1 = part + (size_t)4096*DM;
  const float4 a0 = *(const float4*)(part + i);
  const float4 a1 = *(const float4*)(part + i + 4);
  const float4 c0 = *(const float4*)(p1 + i);
  const float4 c1 = *(const float4*)(p1 + i + 4);
  const us4 x0 = *(const us4*)(xn + i);
  const us4 x1 = *(const us4*)(xn + i + 4);
  const float4 b0 = *(const float4*)(b2 + col);
  const float4 b1 = *(const float4*)(b2 + col + 4);
  float4 o0, o1;
  o0.x = a0.x + c0.x + bf2f(x0[0]) + b0.x;
  o0.y = a0.y + c0.y + bf2f(x0[1]) + b0.y;
  o0.z = a0.z + c0.z + bf2f(x0[2]) + b0.z;
  o0.w = a0.w + c0.w + bf2f(x0[3]) + b0.w;
  o1.x = a1.x + c1.x + bf2f(x1[0]) + b1.x;
  o1.y = a1.y + c1.y + bf2f(x1[1]) + b1.y;
  o1.z = a1.z + c1.z + bf2f(x1[2]) + b1.z;
  o1.w = a1.w + c1.w + bf2f(x1[3]) + b1.w;
  *(float4*)(out + i)     = o0;
  *(float4*)(out + i + 4) = o1;
}

// ---------------------------------------------------------------------------
// Banded attention (r9 form — best measured): 8-wave blocks, single-buffered
// K/V chunks, wave-uniform full-valid fast path, v_cvt_pk_bf16_f32 packing.
// ---------------------------------------------------------------------------
__global__ __launch_bounds__(512, 6)
void attn_kernel(const ushort_t* __restrict__ Q, const ushort_t* __restrict__ Kw,
                 const ushort_t* __restrict__ Vt, const float* __restrict__ x,
                 ushort_t* __restrict__ xattn)
{
  __shared__ ushort_t Ks[64*64];
  __shared__ ushort_t Vs[64*64];
  __shared__ ushort_t P_lds[8][16][72];
  const int t = threadIdx.x, w = t>>6, l = t&63;
  const int qb = blockIdx.x, bh = blockIdx.y;
  const int b = bh/NH, h = bh%NH;
  const int qs = qb*128 + w*16;
  const int lq = l&15, lg = l>>4;
  const int i_q = qs + lq;
  const int kwin0 = qb*128 - 256;

  const int lo = w*16 - 63;
  const int cmin = lo > 0 ? ((lo+63)>>6) : 0;
  int cmax = (w*16 + 527) >> 6; if (cmax > 9) cmax = 9;

  const ushort_t* Qp = Q  + ((size_t)b*S0 + qs)*DM + h*DH;
  const ushort_t* Kp = Kw + (size_t)b*KS*DM + h*DH;
  const ushort_t* Vp = Vt + (size_t)bh*DH*KS;

  const bf16x8 qf0 = *(const bf16x8*)(Qp + (size_t)lq*DM + lg*8);
  const bf16x8 qf1 = *(const bf16x8*)(Qp + (size_t)lq*DM + 32 + lg*8);

  const int rl = l>>3;
  const int sslot = (l&7) ^ rl;

  const f32x4 zero = {0.f,0.f,0.f,0.f};
  f32x4 accO[4];
  #pragma unroll
  for (int g=0; g<4; g++) accO[g] = zero;
  float lsum = 0.f;

  auto stage = [&](int c){
    const int kbase = kwin0 + c*64;
    const int ck = w*8 + rl;
    int krow = kbase + ck; if (krow < 0) krow = 0;
    lds_cp16(Kp + (size_t)krow*DM + sslot*8, &Ks[(w*8)*64]);
    int kcol = kbase + sslot*8; if (kcol < 0) kcol = 0;
    lds_cp16(Vp + (size_t)ck*KS + kcol,      &Vs[(w*8)*64]);
  };

  stage(0);
  __syncthreads();
  for (int c=0; c<10; ++c){
    if (c >= cmin && c <= cmax){
      const int kbase = kwin0 + c*64;
      const bool fullv = (kbase >= 0) && (kbase + 63 < GK) &&
                         (kbase >= qs - 241) && (kbase <= qs + 193);
      const int slot0 = ((lg ^ (lq&7)) << 3);
      #pragma unroll
      for (int sb=0; sb<4; sb++){
        const bf16x8 kf0 = *(const bf16x8*)&Ks[(sb*16+lq)*64 + slot0];
        const bf16x8 kf1 = *(const bf16x8*)&Ks[(sb*16+lq)*64 + (slot0^32)];
        f32x4 s = zero;
        s = __builtin_amdgcn_mfma_f32_16x16x32_bf16(kf0, qf0, s, 0,0,0);
        s = __builtin_amdgcn_mfma_f32_16x16x32_bf16(kf1, qf1, s, 0,0,0);
        float pv[4];
        if (fullv){
          #pragma unroll
          for (int r=0; r<4; r++) pv[r] = __expf(s[r]);
        } else {
          #pragma unroll
          for (int r=0; r<4; r++){
            const int j = kbase + sb*16 + lg*4 + r;
            const bool valid = (j >= 0) && (j < GK) && (j >= i_q-256) && (j <= i_q+256);
            pv[r] = valid ? __expf(s[r]) : 0.f;
          }
        }
        lsum += (pv[0]+pv[1]) + (pv[2]+pv[3]);
        unsigned a0, a1;
        asm("v_cvt_pk_bf16_f32 %0, %1, %2" : "=v"(a0) : "v"(pv[0]), "v"(pv[1]));
        asm("v_cvt_pk_bf16_f32 %0, %1, %2" : "=v"(a1) : "v"(pv[2]), "v"(pv[3]));
        uint2 pk2; pk2.x = a0; pk2.y = a1;
        *(uint2*)&P_lds[w][lq][sb*16 + lg*4] = pk2;
      }
      #pragma unroll
      for (int r2=0; r2<2; r2++){
        const bf16x8 pf = *(const bf16x8*)&P_lds[w][lq][r2*32 + lg*8];
        #pragma unroll
        for (int g=0; g<4; g++){
          const int vslot = ((((r2<<2)|lg) ^ (lq&7)) << 3);
          const bf16x8 vtf = *(const bf16x8*)&Vs[(g*16+lq)*64 + vslot];
          accO[g] = __builtin_amdgcn_mfma_f32_16x16x32_bf16(vtf, pf, accO[g], 0,0,0);
        }
      }
    }
    __syncthreads();
    if (c+1 < 10){
      stage(c+1);
      __syncthreads();
    }
  }

  // ---- global-key slot ----
  {
    const ushort_t* kr = Kp + (size_t)(GK+lq)*DM + lg*8;
    const bf16x8 kf0 = *(const bf16x8*)(kr);
    const bf16x8 kf1 = *(const bf16x8*)(kr + 32);
    f32x4 s = zero;
    s = __builtin_amdgcn_mfma_f32_16x16x32_bf16(kf0, qf0, s, 0,0,0);
    s = __builtin_amdgcn_mfma_f32_16x16x32_bf16(kf1, qf1, s, 0,0,0);
    us4 pk, pz;
    #pragma unroll
    for (int r=0; r<4; r++){
      const float p = (lg==0 && r==0) ? __expf(s[r]) : 0.f;
      lsum += p;
      pk[r] = f2bf(p);
      pz[r] = 0;
    }
    *(us4*)&P_lds[w][lq][lg*4] = pk;
    *(us4*)&P_lds[w][lq][16 + lg*4] = pz;
    const bf16x8 pf = *(const bf16x8*)&P_lds[w][lq][lg*8];
    const int kb_lane = GK + (lg&1)*8;
    #pragma unroll
    for (int g=0; g<4; g++){
      const bf16x8 vtf = *(const bf16x8*)(Vp + (size_t)(g*16 + lq)*KS + kb_lane);
      accO[g] = __builtin_amdgcn_mfma_f32_16x16x32_bf16(vtf, pf, accO[g], 0,0,0);
    }
  }

  lsum += __shfl_xor(lsum, 16);
  lsum += __shfl_xor(lsum, 32);
  const float inv = 1.f / lsum;

  const float* xr = x + ((size_t)b*S0 + i_q)*DM + h*DH;
  ushort_t* outp = xattn + ((size_t)b*S0 + i_q)*DM + h*DH;
  #pragma unroll
  for (int g=0; g<4; g++){
    const float4 xv = *(const float4*)(xr + g*16 + lg*4);
    us4 o;
    o[0] = f2bf(accO[g][0]*inv + xv.x);
    o[1] = f2bf(accO[g][1]*inv + xv.y);
    o[2] = f2bf(accO[g][2]*inv + xv.z);
    o[3] = f2bf(accO[g][3]*inv + xv.w);
    *(us4*)(outp + g*16 + lg*4) = o;
  }
}

// ---------------------------------------------------------------------------
// LayerNorm over D=768, bf16 in/out. grid = 4096 rows, 192 threads.
// ---------------------------------------------------------------------------
__global__ __launch_bounds__(192)
void ln_kernel(const ushort_t* __restrict__ xattn, const float* __restrict__ gam,
               const float* __restrict__ bet, ushort_t* __restrict__ xn)
{
  const int row = blockIdx.x, t = threadIdx.x;
  const us4 xv = *(const us4*)(xattn + (size_t)row*DM + t*4);
  float v[4];
  float s = 0.f, ss = 0.f;
  #pragma unroll
  for (int r=0;r<4;r++){ v[r] = bf2f(xv[r]); s += v[r]; ss += v[r]*v[r]; }
  #pragma unroll
  for (int o=1; o<64; o<<=1){ s += __shfl_xor(s,o); ss += __shfl_xor(ss,o); }
  __shared__ float red[3][2];
  if ((t&63)==0){ red[t>>6][0]=s; red[t>>6][1]=ss; }
  __syncthreads();
  const float S  = red[0][0]+red[1][0]+red[2][0];
  const float SS = red[0][1]+red[1][1]+red[2][1];
  const float mu = S*(1.f/768.f);
  const float var = SS*(1.f/768.f) - mu*mu;
  const float rs = rsqrtf(var + 1e-5f);
  const float4 g4 = *(const float4*)(gam + t*4);
  const float4 b4 = *(const float4*)(bet + t*4);
  us4 o;
  o[0] = f2bf((v[0]-mu)*rs*g4.x + b4.x);
  o[1] = f2bf((v[1]-mu)*rs*g4.y + b4.y);
  o[2] = f2bf((v[2]-mu)*rs*g4.z + b4.z);
  o[3] = f2bf((v[3]-mu)*rs*g4.w + b4.w);
  *(us4*)(xn + (size_t)row*DM + t*4) = o;
}

// ---------------------------------------------------------------------------
extern "C" void kernel_launch(void* const* d_in, const int* in_sizes, int n_in,
                              void* d_out, int out_size, void* d_ws, size_t ws_size,
                              hipStream_t stream)
{
  const float* x   = (const float*)d_in[0];
  const float* Wq  = (const float*)d_in[2];
  const float* bq  = (const float*)d_in[3];
  const float* Wk  = (const float*)d_in[4];
  const float* bk  = (const float*)d_in[5];
  const float* Wv  = (const float*)d_in[6];
  const float* bv  = (const float*)d_in[7];
  const float* lng = (const float*)d_in[14];
  const float* lnb = (const float*)d_in[15];
  const float* W1  = (const float*)d_in[16];
  const float* b1  = (const float*)d_in[17];
  const float* W2  = (const float*)d_in[18];
  const float* b2  = (const float*)d_in[19];
  float* out = (float*)d_out;

  char* ws = (char*)d_ws;
  ushort_t* xb  = (ushort_t*)(ws + 0);          //  6,291,456
  ushort_t* Qb  = (ushort_t*)(ws + 6291456);    //  6,291,456
  ushort_t* Kb  = (ushort_t*)(ws + 12582912);   //  7,274,496 (2 x KS x 768)
  ushort_t* Vtb = (ushort_t*)(ws + 19857408);   //  7,274,496 (24 x 64 x KS)
  ushort_t* hb  = (ushort_t*)(ws + 0);          // 25,165,824 — reuses xb..Vtb
  size_t o2 = 27131904;
  ushort_t* WtQ = (ushort_t*)(ws + o2); o2 += 1179648;   // rows 0..767   of fused Bt
  ushort_t* WtK = (ushort_t*)(ws + o2); o2 += 1179648;   // rows 768..1535
  ushort_t* WtV = (ushort_t*)(ws + o2); o2 += 1179648;   // rows 1536..2303
  ushort_t* Wt1 = (ushort_t*)(ws + o2); o2 += 4718592;   // 3072 x 768
  ushort_t* Wt2 = (ushort_t*)(ws + o2); o2 += 4718592;   // 768 x 3072
  ushort_t* xat = (ushort_t*)(ws + o2); o2 += 6291456;   // 4096 x 768 bf16
  ushort_t* xnb = (ushort_t*)(ws + o2); o2 += 6291456;   // 4096 x 768 bf16
  float*    bqkv= (float*)   (ws + o2); o2 += 9216;      // 2304 fp32
  float*    part= (float*)   (ws + o2); o2 += 25165824;  // 2 x 4096 x 768 fp32
  (void)ws_size; (void)in_sizes; (void)n_in; (void)out_size;

  // batched prep
  prep_kernel<<<4905,256,0,stream>>>(Wq, Wk, Wv, W1, W2, x, bq, bk, bv,
                                     WtQ, WtK, WtV, Wt1, Wt2, xb, bqkv, Kb, Vtb);

  // fused QKV projection: 128x64 tiles, 36x32 = 1152 WGs (4.5 blocks/CU)
  gemm_bt<4,2,ushort_t><<<1152,256,0,stream>>>(xb, WtQ, bqkv, Qb, Kb, Vtb,
                                               768, 768, 0LL, 36);

  // attention + residual (bf16 out): r9 single-buffer form
  attn_kernel<<<dim3(16,24),512,0,stream>>>(Qb, Kb, Vtb, x, xat);

  // LayerNorm
  ln_kernel<<<4096,192,0,stream>>>(xat, lng, lnb, xnb);

  // FFN1: 128x64 tiles, 48x32 = 1536 WGs (6 blocks/CU), fast GELU
  gemm_bt<2,2,ushort_t><<<1536,256,0,stream>>>(xnb, Wt1, b1, hb, nullptr, nullptr,
                                               768, 3072, 2048LL*3072, 48);
  // FFN2: split-K=2, 128x64 tiles, m97 loop, partials + reduce
  gemm_sk<<<768,256,0,stream>>>(hb, Wt2, part);
  ffn2_reduce<<<1536,256,0,stream>>>(part, xnb, b2, out);
}

// Round 16
// 136.688 us; speedup vs baseline: 1.0669x; 1.0669x over previous
//
#include <hip/hip_runtime.h>
#include <hip/hip_bf16.h>

typedef unsigned short ushort_t;
typedef __attribute__((ext_vector_type(8))) __bf16 bf16x8;
typedef __attribute__((ext_vector_type(4))) float f32x4;
typedef __attribute__((ext_vector_type(4))) unsigned short us4;

#define S0 2048
#define DM 768
#define NH 12
#define DH 64
#define KS 2368   // allocated key rows per batch (2048 real + bias pad, global key at 2304)
#define GK 2304   // global-key row index

__device__ __forceinline__ float bf2f(ushort_t h){
  union{unsigned u; float f;} x; x.u = ((unsigned)h)<<16; return x.f;
}
__device__ __forceinline__ ushort_t f2bf(float f){
  union{float f; unsigned u;} x; x.f = f;
  unsigned r = (x.u + 0x7FFFu + ((x.u>>16)&1u))>>16;
  return (ushort_t)r;
}

// fast GELU (sigmoid form of the tanh approximation; ~8 VALU vs ~35 for erff;
// saturates correctly at both ends). |err| vs exact < 5e-4.
__device__ __forceinline__ float gelu_fast(float u){
  const float t = u*u;
  const float arg = u*(-1.5957691216f - 0.0713548163f*t);
  return u / (1.f + __expf(arg));
}

typedef void as1_void __attribute__((address_space(1)));
typedef void as3_void __attribute__((address_space(3)));
__device__ __forceinline__ void lds_cp16(const void* g, void* s){
  __builtin_amdgcn_global_load_lds((as1_void*)g, (as3_void*)s, 16, 0, 0);
}

// bijective XCD-chunk swizzle (m204)
__device__ __forceinline__ int xcd_swizzle(int bid, int nwg){
  const int q8 = nwg>>3, r8 = nwg&7;
  const int xcd = bid & 7, sub = bid >> 3;
  return (xcd < r8 ? xcd*(q8+1) : r8*(q8+1) + (xcd-r8)*q8) + sub;
}

// ---------------------------------------------------------------------------
// Batched prep: weight transposes + x cvt + bias concat + K/Vt bias fills
// ---------------------------------------------------------------------------
__global__ __launch_bounds__(256)
void prep_kernel(const float* __restrict__ Wq, const float* __restrict__ Wk,
                 const float* __restrict__ Wv, const float* __restrict__ W1,
                 const float* __restrict__ W2, const float* __restrict__ x,
                 const float* __restrict__ bq, const float* __restrict__ bk,
                 const float* __restrict__ bv,
                 ushort_t* __restrict__ WtQ, ushort_t* __restrict__ WtK,
                 ushort_t* __restrict__ WtV, ushort_t* __restrict__ Wt1,
                 ushort_t* __restrict__ Wt2, ushort_t* __restrict__ xb,
                 float* __restrict__ bqkv, ushort_t* __restrict__ Kb,
                 ushort_t* __restrict__ Vtb)
{
  __shared__ ushort_t tile[64][72];
  const int id = blockIdx.x, t = threadIdx.x;
  if (id < 1584){
    const float* src; ushort_t* dst; int K, N, bx, by;
    if (id < 432){
      const int m = id/144, r = id%144;
      src = (m==0)?Wq:((m==1)?Wk:Wv);
      dst = (m==0)?WtQ:((m==1)?WtK:WtV);
      K=768; N=768; bx=r%12; by=r/12;
    } else if (id < 1008){
      const int r = id-432; src=W1; dst=Wt1; K=768; N=3072; bx=r%48; by=r/48;
    } else {
      const int r = id-1008; src=W2; dst=Wt2; K=3072; N=768; bx=r%12; by=r/12;
    }
    const int n0 = bx*64, k0 = by*64;
    #pragma unroll
    for (int p=0; p<2; p++){
      int r = (t>>3) + p*32, c = (t&7)*8;
      const float* sp = src + (size_t)(k0+r)*N + n0 + c;
      const float4 a = *(const float4*)sp;
      const float4 b = *(const float4*)(sp+4);
      ushort_t v[8] = { f2bf(a.x), f2bf(a.y), f2bf(a.z), f2bf(a.w),
                        f2bf(b.x), f2bf(b.y), f2bf(b.z), f2bf(b.w) };
      *(int4*)&tile[r][c] = *(int4*)v;
    }
    __syncthreads();
    #pragma unroll
    for (int p=0; p<2; p++){
      int n = t&63, kc = (t>>6)*8 + p*32;
      ushort_t v[8];
      #pragma unroll
      for (int e=0; e<8; e++) v[e] = tile[kc+e][n];
      *(int4*)(dst + (size_t)(n0+n)*K + k0 + kc) = *(int4*)v;
    }
  } else if (id < 3120){
    const int i = (id-1584)*2048 + t*8;
    const float4 a = *(const float4*)(x+i);
    const float4 b = *(const float4*)(x+i+4);
    ushort_t v[8] = { f2bf(a.x), f2bf(a.y), f2bf(a.z), f2bf(a.w),
                      f2bf(b.x), f2bf(b.y), f2bf(b.z), f2bf(b.w) };
    *(int4*)(xb+i) = *(int4*)v;
  } else if (id < 3129){
    const int i = (id-3120)*256 + t;
    if (i < 2304)
      bqkv[i] = (i < 768) ? bq[i] : (i < 1536) ? bk[i-768] : bv[i-1536];
  } else if (id < 3369){
    const int i = (id-3129)*2048 + t*8;
    const int col = i % DM;
    const int rr  = i / DM;
    const int row = S0 + rr % (KS-S0);
    const int bb  = rr / (KS-S0);
    const float4 a = *(const float4*)(bk+col);
    const float4 b4 = *(const float4*)(bk+col+4);
    ushort_t v[8] = { f2bf(a.x), f2bf(a.y), f2bf(a.z), f2bf(a.w),
                      f2bf(b4.x), f2bf(b4.y), f2bf(b4.z), f2bf(b4.w) };
    *(int4*)&Kb[(size_t)bb*KS*DM + (size_t)row*DM + col] = *(int4*)v;
  } else {
    const int rid = id - 3369;
    const int h = (rid>>6) % NH;
    const int dd = rid & 63;
    const ushort_t val = f2bf(bv[h*64+dd]);
    if (t < 80){
      us4 pk = {val, val, val, val};
      *(us4*)&Vtb[(size_t)rid*KS + S0 + t*4] = pk;
    }
  }
}

// ---------------------------------------------------------------------------
// GEMM 128 x (32*NF), BK=64, 4 waves (2x2). m97 single-buffer structure,
// both-sides XOR swizzle (T2), XCD block swizzle (T1).
// EPI: 2 fast GELU, 4 fused-QKV routing (Q scaled / K batched / Vt direct).
// Grid discipline: keep blocks/CU an exact integer (fractional occupancy
// imbalance cost ~10% — measured r15).
// ---------------------------------------------------------------------------
template<int EPI, int NF, typename OT>
__global__ __launch_bounds__(256)
void gemm_bt(const ushort_t* __restrict__ A, const ushort_t* __restrict__ Bt,
             const float* __restrict__ bias, OT* __restrict__ C,
             ushort_t* __restrict__ C2, ushort_t* __restrict__ C3,
             int K, int ldc, long long ldcb, int nbx)
{
  __shared__ ushort_t As[128*64];
  __shared__ ushort_t Bs[NF*32*64];
  const int tid = threadIdx.x, wid = tid>>6, l = tid&63;

  const int wg = xcd_swizzle(blockIdx.x, gridDim.x);
  const int bx = wg % nbx, by = wg / nbx;
  const int m0 = by*128, n0 = bx*(NF*32);

  const int wm = wid>>1, wn = wid&1;
  const int lq = l&15, lg = l>>4;
  const int xa = lq&7;

  f32x4 acc[4][NF];
  const f32x4 zero = {0.f,0.f,0.f,0.f};
  #pragma unroll
  for (int i=0;i<4;i++)
    #pragma unroll
    for (int j=0;j<NF;j++) acc[i][j] = zero;

  const int swzc = ((l&7) ^ ((l>>3)&7)) * 8;
  const ushort_t* Ag = A  + (size_t)(m0 + wid*32 + (l>>3))*K + swzc;
  const ushort_t* Bg = Bt + (size_t)(n0 + wid*(NF*8) + (l>>3))*K + swzc;

  for (int k0=0; k0<K; k0+=64){
    #pragma unroll
    for (int i=0;i<4;i++)
      lds_cp16(Ag + (size_t)i*8*K + k0, As + wid*2048 + i*512);
    #pragma unroll
    for (int i=0;i<NF;i++)
      lds_cp16(Bg + (size_t)i*8*K + k0, Bs + wid*(NF*512) + i*512);
    __syncthreads();
    #pragma unroll
    for (int kk=0; kk<64; kk+=32){
      bf16x8 af[4], bfr[NF];
      #pragma unroll
      for (int mi=0;mi<4;mi++)
        af[mi] = *(const bf16x8*)&As[(wm*64+mi*16+lq)*64 + ((((kk>>3)+lg)^xa)<<3)];
      #pragma unroll
      for (int ni=0;ni<NF;ni++)
        bfr[ni] = *(const bf16x8*)&Bs[(wn*(NF*16)+ni*16+lq)*64 + ((((kk>>3)+lg)^xa)<<3)];
      #pragma unroll
      for (int mi=0;mi<4;mi++)
        #pragma unroll
        for (int ni=0;ni<NF;ni++)
          acc[mi][ni] = __builtin_amdgcn_mfma_f32_16x16x32_bf16(af[mi], bfr[ni], acc[mi][ni], 0,0,0);
    }
    __syncthreads();
  }

  if (EPI==4){
    const int seg = n0 / 768;                 // 0:Q 1:K 2:Vt (tiles never straddle)
    if (seg == 2){
      #pragma unroll
      for (int mi=0;mi<4;mi++){
        const int mrow = m0 + wm*64 + mi*16 + lg*4;
        const int bb = mrow>>11, key = mrow&2047;
        #pragma unroll
        for (int ni=0;ni<NF;ni++){
          const int ncol = n0 + wn*(NF*16) + ni*16 + lq;
          const int col = ncol - 1536;
          const float bvv = bias[ncol];
          us4 pk;
          #pragma unroll
          for (int r=0;r<4;r++) pk[r] = f2bf(acc[mi][ni][r] + bvv);
          *(us4*)&C3[((size_t)(bb*NH + (col>>6))*64 + (col&63))*KS + key] = pk;
        }
      }
      return;
    }
    ushort_t* dst = (seg==0) ? (ushort_t*)C : C2;
    const long long bstride = (seg==1) ? (long long)KS*DM : 2048LL*DM;
    const float sc = (seg==0) ? 0.125f : 1.f;
    #pragma unroll
    for (int mi=0;mi<4;mi++){
      const int mrow = m0 + wm*64 + mi*16 + lg*4;
      #pragma unroll
      for (int ni=0;ni<NF;ni++){
        const int ncol = n0 + wn*(NF*16) + ni*16 + lq;
        const float bv = bias[ncol];
        const int col = ncol - seg*768;
        #pragma unroll
        for (int r=0;r<4;r++){
          const int m = mrow + r;
          const float v = (acc[mi][ni][r] + bv)*sc;
          dst[(size_t)((long long)(m>>11)*bstride) + (size_t)(m&2047)*DM + col] = f2bf(v);
        }
      }
    }
    return;
  }

  #pragma unroll
  for (int mi=0;mi<4;mi++){
    const int mrow = m0 + wm*64 + mi*16 + lg*4;
    #pragma unroll
    for (int ni=0;ni<NF;ni++){
      const int ncol = n0 + wn*(NF*16) + ni*16 + lq;
      const float bv = bias[ncol];
      #pragma unroll
      for (int r=0;r<4;r++){
        const int m = mrow + r;
        float v = acc[mi][ni][r] + bv;
        if (EPI==2) v = gelu_fast(v);
        const size_t caddr = (size_t)((long long)(m>>11)*ldcb) + (size_t)(m&2047)*ldc + ncol;
        C[caddr] = f2bf(v);
      }
    }
  }
}

// ---------------------------------------------------------------------------
// FFN2 split-K=2, 128x64 tiles, m97 single-buffer loop. grid = 768 WGs.
// Partials fp32, reduced by ffn2_reduce (no atomics).
// ---------------------------------------------------------------------------
__global__ __launch_bounds__(256)
void gemm_sk(const ushort_t* __restrict__ A, const ushort_t* __restrict__ Bt,
             float* __restrict__ part)
{
  __shared__ ushort_t As[128*64];
  __shared__ ushort_t Bs[64*64];
  const int tid = threadIdx.x, wid = tid>>6, l = tid&63;

  const int wg = xcd_swizzle(blockIdx.x, gridDim.x);
  const int p = wg / 384, rem = wg % 384;      // p: K-half
  const int bx = rem % 12, by = rem / 12;
  const int m0 = by*128, n0 = bx*64;
  const int kbeg = p*1536;

  const int wm = wid>>1, wn = wid&1;
  const int lq = l&15, lg = l>>4;
  const int xa = lq&7;

  f32x4 acc[4][2];
  const f32x4 zero = {0.f,0.f,0.f,0.f};
  #pragma unroll
  for (int i=0;i<4;i++){ acc[i][0]=zero; acc[i][1]=zero; }

  const int swzc = ((l&7) ^ ((l>>3)&7)) * 8;
  const ushort_t* Ag = A  + (size_t)(m0 + wid*32 + (l>>3))*3072 + kbeg + swzc;
  const ushort_t* Bg = Bt + (size_t)(n0 + wid*16 + (l>>3))*3072 + kbeg + swzc;

  for (int k0=0; k0<1536; k0+=64){
    #pragma unroll
    for (int i=0;i<4;i++)
      lds_cp16(Ag + (size_t)i*8*3072 + k0, As + wid*2048 + i*512);
    #pragma unroll
    for (int i=0;i<2;i++)
      lds_cp16(Bg + (size_t)i*8*3072 + k0, Bs + wid*1024 + i*512);
    __syncthreads();
    #pragma unroll
    for (int kk=0; kk<64; kk+=32){
      bf16x8 af[4], bfr[2];
      #pragma unroll
      for (int mi=0;mi<4;mi++)
        af[mi] = *(const bf16x8*)&As[(wm*64+mi*16+lq)*64 + ((((kk>>3)+lg)^xa)<<3)];
      #pragma unroll
      for (int ni=0;ni<2;ni++)
        bfr[ni] = *(const bf16x8*)&Bs[(wn*32+ni*16+lq)*64 + ((((kk>>3)+lg)^xa)<<3)];
      #pragma unroll
      for (int mi=0;mi<4;mi++)
        #pragma unroll
        for (int ni=0;ni<2;ni++)
          acc[mi][ni] = __builtin_amdgcn_mfma_f32_16x16x32_bf16(af[mi], bfr[ni], acc[mi][ni], 0,0,0);
    }
    __syncthreads();
  }

  float* dst = part + (size_t)p*4096*DM;
  #pragma unroll
  for (int mi=0;mi<4;mi++){
    const int mrow = m0 + wm*64 + mi*16 + lg*4;
    #pragma unroll
    for (int ni=0;ni<2;ni++){
      const int ncol = n0 + wn*32 + ni*16 + lq;
      #pragma unroll
      for (int r=0;r<4;r++)
        dst[(size_t)(mrow+r)*DM + ncol] = acc[mi][ni][r];
    }
  }
}

// ---------------------------------------------------------------------------
// FFN2 reduce: out = part0 + part1 + xn + b2. 8 elems/thread, 1536 WGs.
// ---------------------------------------------------------------------------
__global__ __launch_bounds__(256)
void ffn2_reduce(const float* __restrict__ part, const ushort_t* __restrict__ xn,
                 const float* __restrict__ b2, float* __restrict__ out)
{
  const int i = (blockIdx.x*256 + threadIdx.x)*8;
  const int col = i % DM;                          // 8-aligned, never wraps
  const float* p1 = part + (size_t)4096*DM;
  const float4 a0 = *(const float4*)(part + i);
  const float4 a1 = *(const float4*)(part + i + 4);
  const float4 c0 = *(const float4*)(p1 + i);
  const float4 c1 = *(const float4*)(p1 + i + 4);
  const us4 x0 = *(const us4*)(xn + i);
  const us4 x1 = *(const us4*)(xn + i + 4);
  const float4 b0 = *(const float4*)(b2 + col);
  const float4 b1 = *(const float4*)(b2 + col + 4);
  float4 o0, o1;
  o0.x = a0.x + c0.x + bf2f(x0[0]) + b0.x;
  o0.y = a0.y + c0.y + bf2f(x0[1]) + b0.y;
  o0.z = a0.z + c0.z + bf2f(x0[2]) + b0.z;
  o0.w = a0.w + c0.w + bf2f(x0[3]) + b0.w;
  o1.x = a1.x + c1.x + bf2f(x1[0]) + b1.x;
  o1.y = a1.y + c1.y + bf2f(x1[1]) + b1.y;
  o1.z = a1.z + c1.z + bf2f(x1[2]) + b1.z;
  o1.w = a1.w + c1.w + bf2f(x1[3]) + b1.w;
  *(float4*)(out + i)     = o0;
  *(float4*)(out + i + 4) = o1;
}

// ---------------------------------------------------------------------------
// Banded attention (r9 form — best measured): 8-wave blocks, single-buffered
// K/V chunks, wave-uniform full-valid fast path, v_cvt_pk_bf16_f32 packing.
// ---------------------------------------------------------------------------
__global__ __launch_bounds__(512, 6)
void attn_kernel(const ushort_t* __restrict__ Q, const ushort_t* __restrict__ Kw,
                 const ushort_t* __restrict__ Vt, const float* __restrict__ x,
                 ushort_t* __restrict__ xattn)
{
  __shared__ ushort_t Ks[64*64];
  __shared__ ushort_t Vs[64*64];
  __shared__ ushort_t P_lds[8][16][72];
  const int t = threadIdx.x, w = t>>6, l = t&63;
  const int qb = blockIdx.x, bh = blockIdx.y;
  const int b = bh/NH, h = bh%NH;
  const int qs = qb*128 + w*16;
  const int lq = l&15, lg = l>>4;
  const int i_q = qs + lq;
  const int kwin0 = qb*128 - 256;

  const int lo = w*16 - 63;
  const int cmin = lo > 0 ? ((lo+63)>>6) : 0;
  int cmax = (w*16 + 527) >> 6; if (cmax > 9) cmax = 9;

  const ushort_t* Qp = Q  + ((size_t)b*S0 + qs)*DM + h*DH;
  const ushort_t* Kp = Kw + (size_t)b*KS*DM + h*DH;
  const ushort_t* Vp = Vt + (size_t)bh*DH*KS;

  const bf16x8 qf0 = *(const bf16x8*)(Qp + (size_t)lq*DM + lg*8);
  const bf16x8 qf1 = *(const bf16x8*)(Qp + (size_t)lq*DM + 32 + lg*8);

  const int rl = l>>3;
  const int sslot = (l&7) ^ rl;

  const f32x4 zero = {0.f,0.f,0.f,0.f};
  f32x4 accO[4];
  #pragma unroll
  for (int g=0; g<4; g++) accO[g] = zero;
  float lsum = 0.f;

  auto stage = [&](int c){
    const int kbase = kwin0 + c*64;
    const int ck = w*8 + rl;
    int krow = kbase + ck; if (krow < 0) krow = 0;
    lds_cp16(Kp + (size_t)krow*DM + sslot*8, &Ks[(w*8)*64]);
    int kcol = kbase + sslot*8; if (kcol < 0) kcol = 0;
    lds_cp16(Vp + (size_t)ck*KS + kcol,      &Vs[(w*8)*64]);
  };

  stage(0);
  __syncthreads();
  for (int c=0; c<10; ++c){
    if (c >= cmin && c <= cmax){
      const int kbase = kwin0 + c*64;
      const bool fullv = (kbase >= 0) && (kbase + 63 < GK) &&
                         (kbase >= qs - 241) && (kbase <= qs + 193);
      const int slot0 = ((lg ^ (lq&7)) << 3);
      #pragma unroll
      for (int sb=0; sb<4; sb++){
        const bf16x8 kf0 = *(const bf16x8*)&Ks[(sb*16+lq)*64 + slot0];
        const bf16x8 kf1 = *(const bf16x8*)&Ks[(sb*16+lq)*64 + (slot0^32)];
        f32x4 s = zero;
        s = __builtin_amdgcn_mfma_f32_16x16x32_bf16(kf0, qf0, s, 0,0,0);
        s = __builtin_amdgcn_mfma_f32_16x16x32_bf16(kf1, qf1, s, 0,0,0);
        float pv[4];
        if (fullv){
          #pragma unroll
          for (int r=0; r<4; r++) pv[r] = __expf(s[r]);
        } else {
          #pragma unroll
          for (int r=0; r<4; r++){
            const int j = kbase + sb*16 + lg*4 + r;
            const bool valid = (j >= 0) && (j < GK) && (j >= i_q-256) && (j <= i_q+256);
            pv[r] = valid ? __expf(s[r]) : 0.f;
          }
        }
        lsum += (pv[0]+pv[1]) + (pv[2]+pv[3]);
        unsigned a0, a1;
        asm("v_cvt_pk_bf16_f32 %0, %1, %2" : "=v"(a0) : "v"(pv[0]), "v"(pv[1]));
        asm("v_cvt_pk_bf16_f32 %0, %1, %2" : "=v"(a1) : "v"(pv[2]), "v"(pv[3]));
        uint2 pk2; pk2.x = a0; pk2.y = a1;
        *(uint2*)&P_lds[w][lq][sb*16 + lg*4] = pk2;
      }
      #pragma unroll
      for (int r2=0; r2<2; r2++){
        const bf16x8 pf = *(const bf16x8*)&P_lds[w][lq][r2*32 + lg*8];
        #pragma unroll
        for (int g=0; g<4; g++){
          const int vslot = ((((r2<<2)|lg) ^ (lq&7)) << 3);
          const bf16x8 vtf = *(const bf16x8*)&Vs[(g*16+lq)*64 + vslot];
          accO[g] = __builtin_amdgcn_mfma_f32_16x16x32_bf16(vtf, pf, accO[g], 0,0,0);
        }
      }
    }
    __syncthreads();
    if (c+1 < 10){
      stage(c+1);
      __syncthreads();
    }
  }

  // ---- global-key slot ----
  {
    const ushort_t* kr = Kp + (size_t)(GK+lq)*DM + lg*8;
    const bf16x8 kf0 = *(const bf16x8*)(kr);
    const bf16x8 kf1 = *(const bf16x8*)(kr + 32);
    f32x4 s = zero;
    s = __builtin_amdgcn_mfma_f32_16x16x32_bf16(kf0, qf0, s, 0,0,0);
    s = __builtin_amdgcn_mfma_f32_16x16x32_bf16(kf1, qf1, s, 0,0,0);
    us4 pk, pz;
    #pragma unroll
    for (int r=0; r<4; r++){
      const float p = (lg==0 && r==0) ? __expf(s[r]) : 0.f;
      lsum += p;
      pk[r] = f2bf(p);
      pz[r] = 0;
    }
    *(us4*)&P_lds[w][lq][lg*4] = pk;
    *(us4*)&P_lds[w][lq][16 + lg*4] = pz;
    const bf16x8 pf = *(const bf16x8*)&P_lds[w][lq][lg*8];
    const int kb_lane = GK + (lg&1)*8;
    #pragma unroll
    for (int g=0; g<4; g++){
      const bf16x8 vtf = *(const bf16x8*)(Vp + (size_t)(g*16 + lq)*KS + kb_lane);
      accO[g] = __builtin_amdgcn_mfma_f32_16x16x32_bf16(vtf, pf, accO[g], 0,0,0);
    }
  }

  lsum += __shfl_xor(lsum, 16);
  lsum += __shfl_xor(lsum, 32);
  const float inv = 1.f / lsum;

  const float* xr = x + ((size_t)b*S0 + i_q)*DM + h*DH;
  ushort_t* outp = xattn + ((size_t)b*S0 + i_q)*DM + h*DH;
  #pragma unroll
  for (int g=0; g<4; g++){
    const float4 xv = *(const float4*)(xr + g*16 + lg*4);
    us4 o;
    o[0] = f2bf(accO[g][0]*inv + xv.x);
    o[1] = f2bf(accO[g][1]*inv + xv.y);
    o[2] = f2bf(accO[g][2]*inv + xv.z);
    o[3] = f2bf(accO[g][3]*inv + xv.w);
    *(us4*)(outp + g*16 + lg*4) = o;
  }
}

// ---------------------------------------------------------------------------
// LayerNorm over D=768, bf16 in/out. grid = 4096 rows, 192 threads.
// ---------------------------------------------------------------------------
__global__ __launch_bounds__(192)
void ln_kernel(const ushort_t* __restrict__ xattn, const float* __restrict__ gam,
               const float* __restrict__ bet, ushort_t* __restrict__ xn)
{
  const int row = blockIdx.x, t = threadIdx.x;
  const us4 xv = *(const us4*)(xattn + (size_t)row*DM + t*4);
  float v[4];
  float s = 0.f, ss = 0.f;
  #pragma unroll
  for (int r=0;r<4;r++){ v[r] = bf2f(xv[r]); s += v[r]; ss += v[r]*v[r]; }
  #pragma unroll
  for (int o=1; o<64; o<<=1){ s += __shfl_xor(s,o); ss += __shfl_xor(ss,o); }
  __shared__ float red[3][2];
  if ((t&63)==0){ red[t>>6][0]=s; red[t>>6][1]=ss; }
  __syncthreads();
  const float S  = red[0][0]+red[1][0]+red[2][0];
  const float SS = red[0][1]+red[1][1]+red[2][1];
  const float mu = S*(1.f/768.f);
  const float var = SS*(1.f/768.f) - mu*mu;
  const float rs = rsqrtf(var + 1e-5f);
  const float4 g4 = *(const float4*)(gam + t*4);
  const float4 b4 = *(const float4*)(bet + t*4);
  us4 o;
  o[0] = f2bf((v[0]-mu)*rs*g4.x + b4.x);
  o[1] = f2bf((v[1]-mu)*rs*g4.y + b4.y);
  o[2] = f2bf((v[2]-mu)*rs*g4.z + b4.z);
  o[3] = f2bf((v[3]-mu)*rs*g4.w + b4.w);
  *(us4*)(xn + (size_t)row*DM + t*4) = o;
}

// ---------------------------------------------------------------------------
extern "C" void kernel_launch(void* const* d_in, const int* in_sizes, int n_in,
                              void* d_out, int out_size, void* d_ws, size_t ws_size,
                              hipStream_t stream)
{
  const float* x   = (const float*)d_in[0];
  const float* Wq  = (const float*)d_in[2];
  const float* bq  = (const float*)d_in[3];
  const float* Wk  = (const float*)d_in[4];
  const float* bk  = (const float*)d_in[5];
  const float* Wv  = (const float*)d_in[6];
  const float* bv  = (const float*)d_in[7];
  const float* lng = (const float*)d_in[14];
  const float* lnb = (const float*)d_in[15];
  const float* W1  = (const float*)d_in[16];
  const float* b1  = (const float*)d_in[17];
  const float* W2  = (const float*)d_in[18];
  const float* b2  = (const float*)d_in[19];
  float* out = (float*)d_out;

  char* ws = (char*)d_ws;
  ushort_t* xb  = (ushort_t*)(ws + 0);          //  6,291,456
  ushort_t* Qb  = (ushort_t*)(ws + 6291456);    //  6,291,456
  ushort_t* Kb  = (ushort_t*)(ws + 12582912);   //  7,274,496 (2 x KS x 768)
  ushort_t* Vtb = (ushort_t*)(ws + 19857408);   //  7,274,496 (24 x 64 x KS)
  ushort_t* hb  = (ushort_t*)(ws + 0);          // 25,165,824 — reuses xb..Vtb
  size_t o2 = 27131904;
  ushort_t* WtQ = (ushort_t*)(ws + o2); o2 += 1179648;   // rows 0..767   of fused Bt
  ushort_t* WtK = (ushort_t*)(ws + o2); o2 += 1179648;   // rows 768..1535
  ushort_t* WtV = (ushort_t*)(ws + o2); o2 += 1179648;   // rows 1536..2303
  ushort_t* Wt1 = (ushort_t*)(ws + o2); o2 += 4718592;   // 3072 x 768
  ushort_t* Wt2 = (ushort_t*)(ws + o2); o2 += 4718592;   // 768 x 3072
  ushort_t* xat = (ushort_t*)(ws + o2); o2 += 6291456;   // 4096 x 768 bf16
  ushort_t* xnb = (ushort_t*)(ws + o2); o2 += 6291456;   // 4096 x 768 bf16
  float*    bqkv= (float*)   (ws + o2); o2 += 9216;      // 2304 fp32
  float*    part= (float*)   (ws + o2); o2 += 25165824;  // 2 x 4096 x 768 fp32
  (void)ws_size; (void)in_sizes; (void)n_in; (void)out_size;

  // batched prep
  prep_kernel<<<4905,256,0,stream>>>(Wq, Wk, Wv, W1, W2, x, bq, bk, bv,
                                     WtQ, WtK, WtV, Wt1, Wt2, xb, bqkv, Kb, Vtb);

  // fused QKV projection: 128x96 tiles, 24x32 = 768 WGs (exactly 3 blocks/CU)
  gemm_bt<4,3,ushort_t><<<768,256,0,stream>>>(xb, WtQ, bqkv, Qb, Kb, Vtb,
                                              768, 768, 0LL, 24);

  // attention + residual (bf16 out): r9 single-buffer form
  attn_kernel<<<dim3(16,24),512,0,stream>>>(Qb, Kb, Vtb, x, xat);

  // LayerNorm
  ln_kernel<<<4096,192,0,stream>>>(xat, lng, lnb, xnb);

  // FFN1: 128x64 tiles, 48x32 = 1536 WGs (exactly 6 blocks/CU), fast GELU
  gemm_bt<2,2,ushort_t><<<1536,256,0,stream>>>(xnb, Wt1, b1, hb, nullptr, nullptr,
                                               768, 3072, 2048LL*3072, 48);
  // FFN2: split-K=2, 128x64 tiles, m97 loop, partials + reduce
  gemm_sk<<<768,256,0,stream>>>(hb, Wt2, part);
  ffn2_reduce<<<1536,256,0,stream>>>(part, xnb, b2, out);
}

// Round 17
// 134.271 us; speedup vs baseline: 1.0861x; 1.0180x over previous
//
#include <hip/hip_runtime.h>
#include <hip/hip_bf16.h>

typedef unsigned short ushort_t;
typedef __attribute__((ext_vector_type(8))) __bf16 bf16x8;
typedef __attribute__((ext_vector_type(4))) float f32x4;
typedef __attribute__((ext_vector_type(4))) unsigned short us4;

#define S0 2048
#define DM 768
#define NH 12
#define DH 64
#define KS 2368   // allocated key rows per batch (2048 real + bias pad, global key at 2304)
#define GK 2304   // global-key row index

__device__ __forceinline__ float bf2f(ushort_t h){
  union{unsigned u; float f;} x; x.u = ((unsigned)h)<<16; return x.f;
}
__device__ __forceinline__ ushort_t f2bf(float f){
  union{float f; unsigned u;} x; x.f = f;
  unsigned r = (x.u + 0x7FFFu + ((x.u>>16)&1u))>>16;
  return (ushort_t)r;
}

// fast GELU (sigmoid form of the tanh approximation; ~8 VALU vs ~35 for erff;
// saturates correctly at both ends). |err| vs exact < 5e-4.
__device__ __forceinline__ float gelu_fast(float u){
  const float t = u*u;
  const float arg = u*(-1.5957691216f - 0.0713548163f*t);
  return u / (1.f + __expf(arg));
}

typedef void as1_void __attribute__((address_space(1)));
typedef void as3_void __attribute__((address_space(3)));
__device__ __forceinline__ void lds_cp16(const void* g, void* s){
  __builtin_amdgcn_global_load_lds((as1_void*)g, (as3_void*)s, 16, 0, 0);
}

// bijective XCD-chunk swizzle (m204)
__device__ __forceinline__ int xcd_swizzle(int bid, int nwg){
  const int q8 = nwg>>3, r8 = nwg&7;
  const int xcd = bid & 7, sub = bid >> 3;
  return (xcd < r8 ? xcd*(q8+1) : r8*(q8+1) + (xcd-r8)*q8) + sub;
}

// ---------------------------------------------------------------------------
// Batched prep: weight transposes + x cvt + bias concat + K/Vt bias fills
// ---------------------------------------------------------------------------
__global__ __launch_bounds__(256)
void prep_kernel(const float* __restrict__ Wq, const float* __restrict__ Wk,
                 const float* __restrict__ Wv, const float* __restrict__ W1,
                 const float* __restrict__ W2, const float* __restrict__ x,
                 const float* __restrict__ bq, const float* __restrict__ bk,
                 const float* __restrict__ bv,
                 ushort_t* __restrict__ WtQ, ushort_t* __restrict__ WtK,
                 ushort_t* __restrict__ WtV, ushort_t* __restrict__ Wt1,
                 ushort_t* __restrict__ Wt2, ushort_t* __restrict__ xb,
                 float* __restrict__ bqkv, ushort_t* __restrict__ Kb,
                 ushort_t* __restrict__ Vtb)
{
  __shared__ ushort_t tile[64][72];
  const int id = blockIdx.x, t = threadIdx.x;
  if (id < 1584){
    const float* src; ushort_t* dst; int K, N, bx, by;
    if (id < 432){
      const int m = id/144, r = id%144;
      src = (m==0)?Wq:((m==1)?Wk:Wv);
      dst = (m==0)?WtQ:((m==1)?WtK:WtV);
      K=768; N=768; bx=r%12; by=r/12;
    } else if (id < 1008){
      const int r = id-432; src=W1; dst=Wt1; K=768; N=3072; bx=r%48; by=r/48;
    } else {
      const int r = id-1008; src=W2; dst=Wt2; K=3072; N=768; bx=r%12; by=r/12;
    }
    const int n0 = bx*64, k0 = by*64;
    #pragma unroll
    for (int p=0; p<2; p++){
      int r = (t>>3) + p*32, c = (t&7)*8;
      const float* sp = src + (size_t)(k0+r)*N + n0 + c;
      const float4 a = *(const float4*)sp;
      const float4 b = *(const float4*)(sp+4);
      ushort_t v[8] = { f2bf(a.x), f2bf(a.y), f2bf(a.z), f2bf(a.w),
                        f2bf(b.x), f2bf(b.y), f2bf(b.z), f2bf(b.w) };
      *(int4*)&tile[r][c] = *(int4*)v;
    }
    __syncthreads();
    #pragma unroll
    for (int p=0; p<2; p++){
      int n = t&63, kc = (t>>6)*8 + p*32;
      ushort_t v[8];
      #pragma unroll
      for (int e=0; e<8; e++) v[e] = tile[kc+e][n];
      *(int4*)(dst + (size_t)(n0+n)*K + k0 + kc) = *(int4*)v;
    }
  } else if (id < 3120){
    const int i = (id-1584)*2048 + t*8;
    const float4 a = *(const float4*)(x+i);
    const float4 b = *(const float4*)(x+i+4);
    ushort_t v[8] = { f2bf(a.x), f2bf(a.y), f2bf(a.z), f2bf(a.w),
                      f2bf(b.x), f2bf(b.y), f2bf(b.z), f2bf(b.w) };
    *(int4*)(xb+i) = *(int4*)v;
  } else if (id < 3129){
    const int i = (id-3120)*256 + t;
    if (i < 2304)
      bqkv[i] = (i < 768) ? bq[i] : (i < 1536) ? bk[i-768] : bv[i-1536];
  } else if (id < 3369){
    const int i = (id-3129)*2048 + t*8;
    const int col = i % DM;
    const int rr  = i / DM;
    const int row = S0 + rr % (KS-S0);
    const int bb  = rr / (KS-S0);
    const float4 a = *(const float4*)(bk+col);
    const float4 b4 = *(const float4*)(bk+col+4);
    ushort_t v[8] = { f2bf(a.x), f2bf(a.y), f2bf(a.z), f2bf(a.w),
                      f2bf(b4.x), f2bf(b4.y), f2bf(b4.z), f2bf(b4.w) };
    *(int4*)&Kb[(size_t)bb*KS*DM + (size_t)row*DM + col] = *(int4*)v;
  } else {
    const int rid = id - 3369;
    const int h = (rid>>6) % NH;
    const int dd = rid & 63;
    const ushort_t val = f2bf(bv[h*64+dd]);
    if (t < 80){
      us4 pk = {val, val, val, val};
      *(us4*)&Vtb[(size_t)rid*KS + S0 + t*4] = pk;
    }
  }
}

// ---------------------------------------------------------------------------
// GEMM 128 x (32*NF), BK=64, 4 waves (2x2). m97 single-buffer structure,
// both-sides XOR swizzle (T2), XCD block swizzle (T1).
// EPI: 2 fast GELU, 4 fused-QKV routing (Q scaled / K batched / Vt direct).
// Grid discipline: keep blocks/CU an exact integer (fractional occupancy
// imbalance cost ~10% — measured r15).
// ---------------------------------------------------------------------------
template<int EPI, int NF, typename OT>
__global__ __launch_bounds__(256)
void gemm_bt(const ushort_t* __restrict__ A, const ushort_t* __restrict__ Bt,
             const float* __restrict__ bias, OT* __restrict__ C,
             ushort_t* __restrict__ C2, ushort_t* __restrict__ C3,
             int K, int ldc, long long ldcb, int nbx)
{
  __shared__ ushort_t As[128*64];
  __shared__ ushort_t Bs[NF*32*64];
  const int tid = threadIdx.x, wid = tid>>6, l = tid&63;

  const int wg = xcd_swizzle(blockIdx.x, gridDim.x);
  const int bx = wg % nbx, by = wg / nbx;
  const int m0 = by*128, n0 = bx*(NF*32);

  const int wm = wid>>1, wn = wid&1;
  const int lq = l&15, lg = l>>4;
  const int xa = lq&7;

  f32x4 acc[4][NF];
  const f32x4 zero = {0.f,0.f,0.f,0.f};
  #pragma unroll
  for (int i=0;i<4;i++)
    #pragma unroll
    for (int j=0;j<NF;j++) acc[i][j] = zero;

  const int swzc = ((l&7) ^ ((l>>3)&7)) * 8;
  const ushort_t* Ag = A  + (size_t)(m0 + wid*32 + (l>>3))*K + swzc;
  const ushort_t* Bg = Bt + (size_t)(n0 + wid*(NF*8) + (l>>3))*K + swzc;

  for (int k0=0; k0<K; k0+=64){
    #pragma unroll
    for (int i=0;i<4;i++)
      lds_cp16(Ag + (size_t)i*8*K + k0, As + wid*2048 + i*512);
    #pragma unroll
    for (int i=0;i<NF;i++)
      lds_cp16(Bg + (size_t)i*8*K + k0, Bs + wid*(NF*512) + i*512);
    __syncthreads();
    #pragma unroll
    for (int kk=0; kk<64; kk+=32){
      bf16x8 af[4], bfr[NF];
      #pragma unroll
      for (int mi=0;mi<4;mi++)
        af[mi] = *(const bf16x8*)&As[(wm*64+mi*16+lq)*64 + ((((kk>>3)+lg)^xa)<<3)];
      #pragma unroll
      for (int ni=0;ni<NF;ni++)
        bfr[ni] = *(const bf16x8*)&Bs[(wn*(NF*16)+ni*16+lq)*64 + ((((kk>>3)+lg)^xa)<<3)];
      #pragma unroll
      for (int mi=0;mi<4;mi++)
        #pragma unroll
        for (int ni=0;ni<NF;ni++)
          acc[mi][ni] = __builtin_amdgcn_mfma_f32_16x16x32_bf16(af[mi], bfr[ni], acc[mi][ni], 0,0,0);
    }
    __syncthreads();
  }

  if (EPI==4){
    const int seg = n0 / 768;                 // 0:Q 1:K 2:Vt (tiles never straddle)
    if (seg == 2){
      #pragma unroll
      for (int mi=0;mi<4;mi++){
        const int mrow = m0 + wm*64 + mi*16 + lg*4;
        const int bb = mrow>>11, key = mrow&2047;
        #pragma unroll
        for (int ni=0;ni<NF;ni++){
          const int ncol = n0 + wn*(NF*16) + ni*16 + lq;
          const int col = ncol - 1536;
          const float bvv = bias[ncol];
          us4 pk;
          #pragma unroll
          for (int r=0;r<4;r++) pk[r] = f2bf(acc[mi][ni][r] + bvv);
          *(us4*)&C3[((size_t)(bb*NH + (col>>6))*64 + (col&63))*KS + key] = pk;
        }
      }
      return;
    }
    ushort_t* dst = (seg==0) ? (ushort_t*)C : C2;
    const long long bstride = (seg==1) ? (long long)KS*DM : 2048LL*DM;
    const float sc = (seg==0) ? 0.125f : 1.f;
    #pragma unroll
    for (int mi=0;mi<4;mi++){
      const int mrow = m0 + wm*64 + mi*16 + lg*4;
      #pragma unroll
      for (int ni=0;ni<NF;ni++){
        const int ncol = n0 + wn*(NF*16) + ni*16 + lq;
        const float bv = bias[ncol];
        const int col = ncol - seg*768;
        #pragma unroll
        for (int r=0;r<4;r++){
          const int m = mrow + r;
          const float v = (acc[mi][ni][r] + bv)*sc;
          dst[(size_t)((long long)(m>>11)*bstride) + (size_t)(m&2047)*DM + col] = f2bf(v);
        }
      }
    }
    return;
  }

  #pragma unroll
  for (int mi=0;mi<4;mi++){
    const int mrow = m0 + wm*64 + mi*16 + lg*4;
    #pragma unroll
    for (int ni=0;ni<NF;ni++){
      const int ncol = n0 + wn*(NF*16) + ni*16 + lq;
      const float bv = bias[ncol];
      #pragma unroll
      for (int r=0;r<4;r++){
        const int m = mrow + r;
        float v = acc[mi][ni][r] + bv;
        if (EPI==2) v = gelu_fast(v);
        const size_t caddr = (size_t)((long long)(m>>11)*ldcb) + (size_t)(m&2047)*ldc + ncol;
        C[caddr] = f2bf(v);
      }
    }
  }
}

// ---------------------------------------------------------------------------
// FFN2 split-K=2, 128x64 tiles, m97 single-buffer loop. grid = 768 WGs.
// Partials BF16 (halves partial traffic vs fp32; |part|<~4 so bf16 rounding
// adds <=0.03 absmax vs 0.11 budget). Reduced by ffn2_reduce (no atomics).
// ---------------------------------------------------------------------------
__global__ __launch_bounds__(256)
void gemm_sk(const ushort_t* __restrict__ A, const ushort_t* __restrict__ Bt,
             ushort_t* __restrict__ part)
{
  __shared__ ushort_t As[128*64];
  __shared__ ushort_t Bs[64*64];
  const int tid = threadIdx.x, wid = tid>>6, l = tid&63;

  const int wg = xcd_swizzle(blockIdx.x, gridDim.x);
  const int p = wg / 384, rem = wg % 384;      // p: K-half
  const int bx = rem % 12, by = rem / 12;
  const int m0 = by*128, n0 = bx*64;
  const int kbeg = p*1536;

  const int wm = wid>>1, wn = wid&1;
  const int lq = l&15, lg = l>>4;
  const int xa = lq&7;

  f32x4 acc[4][2];
  const f32x4 zero = {0.f,0.f,0.f,0.f};
  #pragma unroll
  for (int i=0;i<4;i++){ acc[i][0]=zero; acc[i][1]=zero; }

  const int swzc = ((l&7) ^ ((l>>3)&7)) * 8;
  const ushort_t* Ag = A  + (size_t)(m0 + wid*32 + (l>>3))*3072 + kbeg + swzc;
  const ushort_t* Bg = Bt + (size_t)(n0 + wid*16 + (l>>3))*3072 + kbeg + swzc;

  for (int k0=0; k0<1536; k0+=64){
    #pragma unroll
    for (int i=0;i<4;i++)
      lds_cp16(Ag + (size_t)i*8*3072 + k0, As + wid*2048 + i*512);
    #pragma unroll
    for (int i=0;i<2;i++)
      lds_cp16(Bg + (size_t)i*8*3072 + k0, Bs + wid*1024 + i*512);
    __syncthreads();
    #pragma unroll
    for (int kk=0; kk<64; kk+=32){
      bf16x8 af[4], bfr[2];
      #pragma unroll
      for (int mi=0;mi<4;mi++)
        af[mi] = *(const bf16x8*)&As[(wm*64+mi*16+lq)*64 + ((((kk>>3)+lg)^xa)<<3)];
      #pragma unroll
      for (int ni=0;ni<2;ni++)
        bfr[ni] = *(const bf16x8*)&Bs[(wn*32+ni*16+lq)*64 + ((((kk>>3)+lg)^xa)<<3)];
      #pragma unroll
      for (int mi=0;mi<4;mi++)
        #pragma unroll
        for (int ni=0;ni<2;ni++)
          acc[mi][ni] = __builtin_amdgcn_mfma_f32_16x16x32_bf16(af[mi], bfr[ni], acc[mi][ni], 0,0,0);
    }
    __syncthreads();
  }

  ushort_t* dst = part + (size_t)p*4096*DM;
  #pragma unroll
  for (int mi=0;mi<4;mi++){
    const int mrow = m0 + wm*64 + mi*16 + lg*4;
    #pragma unroll
    for (int ni=0;ni<2;ni++){
      const int ncol = n0 + wn*32 + ni*16 + lq;
      #pragma unroll
      for (int r=0;r<4;r++)
        dst[(size_t)(mrow+r)*DM + ncol] = f2bf(acc[mi][ni][r]);
    }
  }
}

// ---------------------------------------------------------------------------
// FFN2 reduce: out = part0 + part1 + xn + b2 (parts bf16). 8 elems/thread.
// ---------------------------------------------------------------------------
__global__ __launch_bounds__(256)
void ffn2_reduce(const ushort_t* __restrict__ part, const ushort_t* __restrict__ xn,
                 const float* __restrict__ b2, float* __restrict__ out)
{
  const int i = (blockIdx.x*256 + threadIdx.x)*8;
  const int col = i % DM;                          // 8-aligned, never wraps
  const ushort_t* p1 = part + (size_t)4096*DM;
  const us4 a0 = *(const us4*)(part + i);
  const us4 a1 = *(const us4*)(part + i + 4);
  const us4 c0 = *(const us4*)(p1 + i);
  const us4 c1 = *(const us4*)(p1 + i + 4);
  const us4 x0 = *(const us4*)(xn + i);
  const us4 x1 = *(const us4*)(xn + i + 4);
  const float4 b0 = *(const float4*)(b2 + col);
  const float4 b1 = *(const float4*)(b2 + col + 4);
  float4 o0, o1;
  o0.x = bf2f(a0[0]) + bf2f(c0[0]) + bf2f(x0[0]) + b0.x;
  o0.y = bf2f(a0[1]) + bf2f(c0[1]) + bf2f(x0[1]) + b0.y;
  o0.z = bf2f(a0[2]) + bf2f(c0[2]) + bf2f(x0[2]) + b0.z;
  o0.w = bf2f(a0[3]) + bf2f(c0[3]) + bf2f(x0[3]) + b0.w;
  o1.x = bf2f(a1[0]) + bf2f(c1[0]) + bf2f(x1[0]) + b1.x;
  o1.y = bf2f(a1[1]) + bf2f(c1[1]) + bf2f(x1[1]) + b1.y;
  o1.z = bf2f(a1[2]) + bf2f(c1[2]) + bf2f(x1[2]) + b1.z;
  o1.w = bf2f(a1[3]) + bf2f(c1[3]) + bf2f(x1[3]) + b1.w;
  *(float4*)(out + i)     = o0;
  *(float4*)(out + i + 4) = o1;
}

// ---------------------------------------------------------------------------
// Banded attention (r9 form — best measured): 8-wave blocks, single-buffered
// K/V chunks, wave-uniform full-valid fast path, v_cvt_pk_bf16_f32 packing.
// ---------------------------------------------------------------------------
__global__ __launch_bounds__(512, 6)
void attn_kernel(const ushort_t* __restrict__ Q, const ushort_t* __restrict__ Kw,
                 const ushort_t* __restrict__ Vt, const float* __restrict__ x,
                 ushort_t* __restrict__ xattn)
{
  __shared__ ushort_t Ks[64*64];
  __shared__ ushort_t Vs[64*64];
  __shared__ ushort_t P_lds[8][16][72];
  const int t = threadIdx.x, w = t>>6, l = t&63;
  const int qb = blockIdx.x, bh = blockIdx.y;
  const int b = bh/NH, h = bh%NH;
  const int qs = qb*128 + w*16;
  const int lq = l&15, lg = l>>4;
  const int i_q = qs + lq;
  const int kwin0 = qb*128 - 256;

  const int lo = w*16 - 63;
  const int cmin = lo > 0 ? ((lo+63)>>6) : 0;
  int cmax = (w*16 + 527) >> 6; if (cmax > 9) cmax = 9;

  const ushort_t* Qp = Q  + ((size_t)b*S0 + qs)*DM + h*DH;
  const ushort_t* Kp = Kw + (size_t)b*KS*DM + h*DH;
  const ushort_t* Vp = Vt + (size_t)bh*DH*KS;

  const bf16x8 qf0 = *(const bf16x8*)(Qp + (size_t)lq*DM + lg*8);
  const bf16x8 qf1 = *(const bf16x8*)(Qp + (size_t)lq*DM + 32 + lg*8);

  const int rl = l>>3;
  const int sslot = (l&7) ^ rl;

  const f32x4 zero = {0.f,0.f,0.f,0.f};
  f32x4 accO[4];
  #pragma unroll
  for (int g=0; g<4; g++) accO[g] = zero;
  float lsum = 0.f;

  auto stage = [&](int c){
    const int kbase = kwin0 + c*64;
    const int ck = w*8 + rl;
    int krow = kbase + ck; if (krow < 0) krow = 0;
    lds_cp16(Kp + (size_t)krow*DM + sslot*8, &Ks[(w*8)*64]);
    int kcol = kbase + sslot*8; if (kcol < 0) kcol = 0;
    lds_cp16(Vp + (size_t)ck*KS + kcol,      &Vs[(w*8)*64]);
  };

  stage(0);
  __syncthreads();
  for (int c=0; c<10; ++c){
    if (c >= cmin && c <= cmax){
      const int kbase = kwin0 + c*64;
      const bool fullv = (kbase >= 0) && (kbase + 63 < GK) &&
                         (kbase >= qs - 241) && (kbase <= qs + 193);
      const int slot0 = ((lg ^ (lq&7)) << 3);
      #pragma unroll
      for (int sb=0; sb<4; sb++){
        const bf16x8 kf0 = *(const bf16x8*)&Ks[(sb*16+lq)*64 + slot0];
        const bf16x8 kf1 = *(const bf16x8*)&Ks[(sb*16+lq)*64 + (slot0^32)];
        f32x4 s = zero;
        s = __builtin_amdgcn_mfma_f32_16x16x32_bf16(kf0, qf0, s, 0,0,0);
        s = __builtin_amdgcn_mfma_f32_16x16x32_bf16(kf1, qf1, s, 0,0,0);
        float pv[4];
        if (fullv){
          #pragma unroll
          for (int r=0; r<4; r++) pv[r] = __expf(s[r]);
        } else {
          #pragma unroll
          for (int r=0; r<4; r++){
            const int j = kbase + sb*16 + lg*4 + r;
            const bool valid = (j >= 0) && (j < GK) && (j >= i_q-256) && (j <= i_q+256);
            pv[r] = valid ? __expf(s[r]) : 0.f;
          }
        }
        lsum += (pv[0]+pv[1]) + (pv[2]+pv[3]);
        unsigned a0, a1;
        asm("v_cvt_pk_bf16_f32 %0, %1, %2" : "=v"(a0) : "v"(pv[0]), "v"(pv[1]));
        asm("v_cvt_pk_bf16_f32 %0, %1, %2" : "=v"(a1) : "v"(pv[2]), "v"(pv[3]));
        uint2 pk2; pk2.x = a0; pk2.y = a1;
        *(uint2*)&P_lds[w][lq][sb*16 + lg*4] = pk2;
      }
      #pragma unroll
      for (int r2=0; r2<2; r2++){
        const bf16x8 pf = *(const bf16x8*)&P_lds[w][lq][r2*32 + lg*8];
        #pragma unroll
        for (int g=0; g<4; g++){
          const int vslot = ((((r2<<2)|lg) ^ (lq&7)) << 3);
          const bf16x8 vtf = *(const bf16x8*)&Vs[(g*16+lq)*64 + vslot];
          accO[g] = __builtin_amdgcn_mfma_f32_16x16x32_bf16(vtf, pf, accO[g], 0,0,0);
        }
      }
    }
    __syncthreads();
    if (c+1 < 10){
      stage(c+1);
      __syncthreads();
    }
  }

  // ---- global-key slot ----
  {
    const ushort_t* kr = Kp + (size_t)(GK+lq)*DM + lg*8;
    const bf16x8 kf0 = *(const bf16x8*)(kr);
    const bf16x8 kf1 = *(const bf16x8*)(kr + 32);
    f32x4 s = zero;
    s = __builtin_amdgcn_mfma_f32_16x16x32_bf16(kf0, qf0, s, 0,0,0);
    s = __builtin_amdgcn_mfma_f32_16x16x32_bf16(kf1, qf1, s, 0,0,0);
    us4 pk, pz;
    #pragma unroll
    for (int r=0; r<4; r++){
      const float p = (lg==0 && r==0) ? __expf(s[r]) : 0.f;
      lsum += p;
      pk[r] = f2bf(p);
      pz[r] = 0;
    }
    *(us4*)&P_lds[w][lq][lg*4] = pk;
    *(us4*)&P_lds[w][lq][16 + lg*4] = pz;
    const bf16x8 pf = *(const bf16x8*)&P_lds[w][lq][lg*8];
    const int kb_lane = GK + (lg&1)*8;
    #pragma unroll
    for (int g=0; g<4; g++){
      const bf16x8 vtf = *(const bf16x8*)(Vp + (size_t)(g*16 + lq)*KS + kb_lane);
      accO[g] = __builtin_amdgcn_mfma_f32_16x16x32_bf16(vtf, pf, accO[g], 0,0,0);
    }
  }

  lsum += __shfl_xor(lsum, 16);
  lsum += __shfl_xor(lsum, 32);
  const float inv = 1.f / lsum;

  const float* xr = x + ((size_t)b*S0 + i_q)*DM + h*DH;
  ushort_t* outp = xattn + ((size_t)b*S0 + i_q)*DM + h*DH;
  #pragma unroll
  for (int g=0; g<4; g++){
    const float4 xv = *(const float4*)(xr + g*16 + lg*4);
    us4 o;
    o[0] = f2bf(accO[g][0]*inv + xv.x);
    o[1] = f2bf(accO[g][1]*inv + xv.y);
    o[2] = f2bf(accO[g][2]*inv + xv.z);
    o[3] = f2bf(accO[g][3]*inv + xv.w);
    *(us4*)(outp + g*16 + lg*4) = o;
  }
}

// ---------------------------------------------------------------------------
// LayerNorm over D=768, bf16 in/out. grid = 4096 rows, 192 threads.
// ---------------------------------------------------------------------------
__global__ __launch_bounds__(192)
void ln_kernel(const ushort_t* __restrict__ xattn, const float* __restrict__ gam,
               const float* __restrict__ bet, ushort_t* __restrict__ xn)
{
  const int row = blockIdx.x, t = threadIdx.x;
  const us4 xv = *(const us4*)(xattn + (size_t)row*DM + t*4);
  float v[4];
  float s = 0.f, ss = 0.f;
  #pragma unroll
  for (int r=0;r<4;r++){ v[r] = bf2f(xv[r]); s += v[r]; ss += v[r]*v[r]; }
  #pragma unroll
  for (int o=1; o<64; o<<=1){ s += __shfl_xor(s,o); ss += __shfl_xor(ss,o); }
  __shared__ float red[3][2];
  if ((t&63)==0){ red[t>>6][0]=s; red[t>>6][1]=ss; }
  __syncthreads();
  const float S  = red[0][0]+red[1][0]+red[2][0];
  const float SS = red[0][1]+red[1][1]+red[2][1];
  const float mu = S*(1.f/768.f);
  const float var = SS*(1.f/768.f) - mu*mu;
  const float rs = rsqrtf(var + 1e-5f);
  const float4 g4 = *(const float4*)(gam + t*4);
  const float4 b4 = *(const float4*)(bet + t*4);
  us4 o;
  o[0] = f2bf((v[0]-mu)*rs*g4.x + b4.x);
  o[1] = f2bf((v[1]-mu)*rs*g4.y + b4.y);
  o[2] = f2bf((v[2]-mu)*rs*g4.z + b4.z);
  o[3] = f2bf((v[3]-mu)*rs*g4.w + b4.w);
  *(us4*)(xn + (size_t)row*DM + t*4) = o;
}

// ---------------------------------------------------------------------------
extern "C" void kernel_launch(void* const* d_in, const int* in_sizes, int n_in,
                              void* d_out, int out_size, void* d_ws, size_t ws_size,
                              hipStream_t stream)
{
  const float* x   = (const float*)d_in[0];
  const float* Wq  = (const float*)d_in[2];
  const float* bq  = (const float*)d_in[3];
  const float* Wk  = (const float*)d_in[4];
  const float* bk  = (const float*)d_in[5];
  const float* Wv  = (const float*)d_in[6];
  const float* bv  = (const float*)d_in[7];
  const float* lng = (const float*)d_in[14];
  const float* lnb = (const float*)d_in[15];
  const float* W1  = (const float*)d_in[16];
  const float* b1  = (const float*)d_in[17];
  const float* W2  = (const float*)d_in[18];
  const float* b2  = (const float*)d_in[19];
  float* out = (float*)d_out;

  char* ws = (char*)d_ws;
  ushort_t* xb  = (ushort_t*)(ws + 0);          //  6,291,456
  ushort_t* Qb  = (ushort_t*)(ws + 6291456);    //  6,291,456
  ushort_t* Kb  = (ushort_t*)(ws + 12582912);   //  7,274,496 (2 x KS x 768)
  ushort_t* Vtb = (ushort_t*)(ws + 19857408);   //  7,274,496 (24 x 64 x KS)
  ushort_t* hb  = (ushort_t*)(ws + 0);          // 25,165,824 — reuses xb..Vtb
  size_t o2 = 27131904;
  ushort_t* WtQ = (ushort_t*)(ws + o2); o2 += 1179648;   // rows 0..767   of fused Bt
  ushort_t* WtK = (ushort_t*)(ws + o2); o2 += 1179648;   // rows 768..1535
  ushort_t* WtV = (ushort_t*)(ws + o2); o2 += 1179648;   // rows 1536..2303
  ushort_t* Wt1 = (ushort_t*)(ws + o2); o2 += 4718592;   // 3072 x 768
  ushort_t* Wt2 = (ushort_t*)(ws + o2); o2 += 4718592;   // 768 x 3072
  ushort_t* xat = (ushort_t*)(ws + o2); o2 += 6291456;   // 4096 x 768 bf16
  ushort_t* xnb = (ushort_t*)(ws + o2); o2 += 6291456;   // 4096 x 768 bf16
  float*    bqkv= (float*)   (ws + o2); o2 += 9216;      // 2304 fp32
  ushort_t* part= (ushort_t*)(ws + o2); o2 += 12582912;  // 2 x 4096 x 768 bf16
  (void)ws_size; (void)in_sizes; (void)n_in; (void)out_size;

  // batched prep
  prep_kernel<<<4905,256,0,stream>>>(Wq, Wk, Wv, W1, W2, x, bq, bk, bv,
                                     WtQ, WtK, WtV, Wt1, Wt2, xb, bqkv, Kb, Vtb);

  // fused QKV projection: 128x96 tiles, 24x32 = 768 WGs (exactly 3 blocks/CU)
  gemm_bt<4,3,ushort_t><<<768,256,0,stream>>>(xb, WtQ, bqkv, Qb, Kb, Vtb,
                                              768, 768, 0LL, 24);

  // attention + residual (bf16 out): r9 single-buffer form
  attn_kernel<<<dim3(16,24),512,0,stream>>>(Qb, Kb, Vtb, x, xat);

  // LayerNorm
  ln_kernel<<<4096,192,0,stream>>>(xat, lng, lnb, xnb);

  // FFN1: 128x64 tiles, 48x32 = 1536 WGs (exactly 6 blocks/CU), fast GELU
  gemm_bt<2,2,ushort_t><<<1536,256,0,stream>>>(xnb, Wt1, b1, hb, nullptr, nullptr,
                                               768, 3072, 2048LL*3072, 48);
  // FFN2: split-K=2, 128x64 tiles, m97 loop, bf16 partials + reduce
  gemm_sk<<<768,256,0,stream>>>(hb, Wt2, part);
  ffn2_reduce<<<1536,256,0,stream>>>(part, xnb, b2, out);
}